// Round 15
// baseline (236.867 us; speedup 1.0000x reference)
//
#include <hip/hip_runtime.h>
#include <hip/hip_bf16.h>
#include <math.h>

#define N 512
#define DIM 64

typedef __attribute__((ext_vector_type(8))) short short8;
typedef __attribute__((ext_vector_type(4))) float f32x4;

// workspace layout (units: floats from base)
#define WS_Q 0
#define WS_B (N*DIM)
#define WS_A (2*N*DIM)
#define WS_ATT (3*N*DIM)
#define WS_MEAN (4*N*DIM)
#define WS_MAXK (4*N*DIM + DIM)       // uint keys
#define WS_KV (4*N*DIM + 2*DIM)       // uint: (bf16(K)<<16)|bf16(V)

__device__ __forceinline__ unsigned short f2bf(float f) {
    unsigned u = __float_as_uint(f);
    return (unsigned short)((u + 0x7fffu + ((u >> 16) & 1u)) >> 16);
}

// native 2^x — one v_exp_f32 (exp2f w/o fast-math is an OCML libcall)
__device__ __forceinline__ float fexp2(float x) {
    float r;
    asm("v_exp_f32 %0, %1" : "=v"(r) : "v"(x));
    return r;
}

// ------------------------------------------------- qkv + A/B + KV-pack
__global__ void k_qkv(const float* __restrict__ feat, const float* __restrict__ Wqkv,
                      const float* __restrict__ bqkv, const float* __restrict__ Wg1,
                      const float* __restrict__ bg1, float* __restrict__ ws) {
    __shared__ float frow[DIM];
    __shared__ float qrow[DIM];
    __shared__ float krow[DIM];
    __shared__ float vrow[DIM];
    int i = blockIdx.x;
    int c = threadIdx.x;              // 0..191
    if (i == 0 && c < DIM) {
        ws[WS_MEAN + c] = 0.0f;
        ((unsigned*)ws)[WS_MAXK + c] = 0u;
    }
    if (c < DIM) frow[c] = feat[i * DIM + c];
    __syncthreads();
    float a0 = bqkv[c], a1 = 0.f, a2 = 0.f, a3 = 0.f;
#pragma unroll
    for (int kk = 0; kk < DIM; kk += 4) {
        a0 += frow[kk + 0] * Wqkv[(kk + 0) * 3 * DIM + c];
        a1 += frow[kk + 1] * Wqkv[(kk + 1) * 3 * DIM + c];
        a2 += frow[kk + 2] * Wqkv[(kk + 2) * 3 * DIM + c];
        a3 += frow[kk + 3] * Wqkv[(kk + 3) * 3 * DIM + c];
    }
    float acc = (a0 + a1) + (a2 + a3);
    if (c < DIM) {
        ws[WS_Q + i * DIM + c] = acc;
        qrow[c] = acc;
    } else if (c < 2 * DIM) {
        krow[c - DIM] = acc;
    } else {
        vrow[c - 2 * DIM] = acc;
    }
    __syncthreads();
    if (c < DIM) {
        float b0 = bg1[c], b1 = 0.f, b2 = 0.f, b3 = 0.f;
#pragma unroll
        for (int kk = 0; kk < DIM; kk += 4) {
            b0 += qrow[kk + 0] * Wg1[(kk + 0) * DIM + c];
            b1 += qrow[kk + 1] * Wg1[(kk + 1) * DIM + c];
            b2 += qrow[kk + 2] * Wg1[(kk + 2) * DIM + c];
            b3 += qrow[kk + 3] * Wg1[(kk + 3) * DIM + c];
        }
        ws[WS_A + i * DIM + c] = (b0 + b1) + (b2 + b3);
    } else if (c < 2 * DIM) {
        int cc = c - DIM;
        float b0 = 0.f, b1 = 0.f, b2 = 0.f, b3 = 0.f;
#pragma unroll
        for (int kk = 0; kk < DIM; kk += 4) {
            b0 += krow[kk + 0] * Wg1[(kk + 0) * DIM + cc];
            b1 += krow[kk + 1] * Wg1[(kk + 1) * DIM + cc];
            b2 += krow[kk + 2] * Wg1[(kk + 2) * DIM + cc];
            b3 += krow[kk + 3] * Wg1[(kk + 3) * DIM + cc];
        }
        ws[WS_B + i * DIM + cc] = (b0 + b1) + (b2 + b3);
    } else {
        int cc = c - 2 * DIM;
        ((unsigned*)ws)[WS_KV + i * DIM + cc] =
            ((unsigned)f2bf(krow[cc]) << 16) | (unsigned)f2bf(vrow[cc]);
    }
}

// ---------------------------------------------------------- fused attention
// one block per query row i; 8 waves x 512 threads; barrier-free main loop.
// Table gathers done on the MATRIX pipe: stacked table T[64 rows = 24x+24y+16z]
// [64 d]; enc[j,:] = onehot(ix, 24+iy, 48+iz) @ T — one-hot bf16 MFMA pair per
// set (q-scaled / LOG2E-scaled / raw). Epilogue per element: ~9 VALU, 0 LDS.
// Deferred-max softmax (rel2 bounded << 127). K/V packed bf16 in ws.
__global__ __launch_bounds__(512) void k_attn(
    const float* __restrict__ dist,
    const float* __restrict__ tx, const float* __restrict__ ty,
    const float* __restrict__ tz, const float* __restrict__ Wg2,
    const float* __restrict__ bg2, float* __restrict__ ws) {
    __shared__ float sT[3 * 64 * 64];     // [set][row 0..63][d]   48 KB
    __shared__ int sidx[N];
    __shared__ float smrg[8][4][16][2];   // [wave][n][l15][{l,a}]

    const int i = blockIdx.x;
    const int tid = threadIdx.x;
    const int w = tid >> 6;          // 0..7
    const int lane = tid & 63;
    const int l15 = lane & 15;
    const int kg = lane >> 4;
    const float LOG2E = 1.4426950408889634f;

    // stage stacked tables: rows 0-23 = tx[set], 24-47 = ty[set], 48-63 = tz[set]
    for (int t = tid; t < 3 * 64 * 64; t += 512) {
        int set = t >> 12, r = (t >> 6) & 63, d = t & 63;
        float v;
        if (r < 24)      v = tx[set * 1536 + r * 64 + d];
        else if (r < 48) v = ty[set * 1536 + (r - 24) * 64 + d];
        else             v = tz[set * 1024 + (r - 48) * 64 + d];
        sT[t] = v;
    }
    // idx quant, pre-offset packed: ix | (24+iy)<<6 | (48+iz)<<12
    for (int j = tid; j < N; j += 512) {
        const float* dp = dist + ((size_t)i * N + j) * 3;
        int ix = min((int)floorf((dp[0] + 3.0f) * 4.0f), 23);
        int iy = min((int)floorf((dp[1] + 3.0f) * 4.0f), 23);
        int iz = min((int)floorf((dp[2] + 2.0f) * 4.0f), 15);
        sidx[j] = ix | ((24 + iy) << 6) | ((48 + iz) << 12);
    }

    float af[2][8];
    {
        const float* ap = ws + WS_A + i * DIM + kg * 8;
#pragma unroll
        for (int ks = 0; ks < 2; ++ks)
#pragma unroll
            for (int e = 0; e < 8; ++e) af[ks][e] = ap[ks * 32 + e];
    }
    float qrn[4], brn[4];
#pragma unroll
    for (int n = 0; n < 4; ++n) {
        qrn[n] = ws[WS_Q + i * DIM + n * 16 + l15] * LOG2E;
        brn[n] = bg2[n * 16 + l15] * LOG2E;
    }

    __syncthreads();   // sT, sidx ready

    // B-fragments: lane holds B[k][d], k = ks*32+kg*8+e, d = n*16+l15
    short8 wB[4][2], fQ[4][2], fK[4][2], fV[4][2];
#pragma unroll
    for (int n = 0; n < 4; ++n) {
        const int dof = n * 16 + l15;
#pragma unroll
        for (int ks = 0; ks < 2; ++ks) {
            union { short8 v; unsigned short u[8]; } tw, tq, tk, tv;
#pragma unroll
            for (int e = 0; e < 8; ++e) {
                int k = ks * 32 + kg * 8 + e;
                tw.u[e] = f2bf(Wg2[k * DIM + dof] * LOG2E);
                float t0 = sT[0 * 4096 + k * 64 + dof];
                float t1 = sT[1 * 4096 + k * 64 + dof];
                float t2 = sT[2 * 4096 + k * 64 + dof];
                tq.u[e] = f2bf(t0 * qrn[n]);
                tk.u[e] = f2bf(t1 * LOG2E);
                tv.u[e] = f2bf(t2);
            }
            wB[n][ks] = tw.v; fQ[n][ks] = tq.v; fK[n][ks] = tk.v; fV[n][ks] = tv.v;
        }
    }

    const float* Bp = ws + WS_B;
    const unsigned* kvp = (const unsigned*)ws + WS_KV;

    float stl[4] = {0.f, 0.f, 0.f, 0.f};
    float sta[4] = {0.f, 0.f, 0.f, 0.f};

    // 32 slices of 16 j; wave w takes slices w, w+8, w+16, w+24
#pragma unroll 2
    for (int t4 = 0; t4 < 4; ++t4) {
        const int j0w = (w + 8 * t4) * 16;
        // H A-fragment (row = j0w + l15)
        short8 h[2];
        {
            const float* bb = Bp + (j0w + l15) * DIM + kg * 8;
#pragma unroll
            for (int ks = 0; ks < 2; ++ks) {
                union { short8 v; unsigned short u[8]; } hh;
#pragma unroll
                for (int e = 0; e < 8; ++e)
                    hh.u[e] = f2bf(fmaxf(af[ks][e] - bb[ks * 32 + e], 0.f));
                h[ks] = hh.v;
            }
        }
        // one-hot A-fragment (row = j0w + l15): 1.0 at k in {ix, 24+iy, 48+iz}
        short8 Aoh[2];
        {
            int pk = sidx[j0w + l15];
            int sx = pk & 63, sy = (pk >> 6) & 63, sz = pk >> 12;
#pragma unroll
            for (int ks = 0; ks < 2; ++ks) {
                union { short8 v; unsigned short u[8]; } aa;
#pragma unroll
                for (int e = 0; e < 8; ++e) {
                    int k = ks * 32 + kg * 8 + e;
                    int sel = (k < 24) ? sx : (k < 48) ? sy : sz;
                    aa.u[e] = (sel == k) ? (unsigned short)0x3F80 : (unsigned short)0;
                }
                Aoh[ks] = aa.v;
            }
        }
#pragma unroll
        for (int n = 0; n < 4; ++n) {
            const int dof = n * 16 + l15;
            f32x4 aW = (f32x4)(brn[n]);
            aW = __builtin_amdgcn_mfma_f32_16x16x32_bf16(h[0], wB[n][0], aW, 0, 0, 0);
            aW = __builtin_amdgcn_mfma_f32_16x16x32_bf16(h[1], wB[n][1], aW, 0, 0, 0);
            f32x4 aQ = (f32x4)(0.f);
            aQ = __builtin_amdgcn_mfma_f32_16x16x32_bf16(Aoh[0], fQ[n][0], aQ, 0, 0, 0);
            aQ = __builtin_amdgcn_mfma_f32_16x16x32_bf16(Aoh[1], fQ[n][1], aQ, 0, 0, 0);
            f32x4 aK = (f32x4)(0.f);
            aK = __builtin_amdgcn_mfma_f32_16x16x32_bf16(Aoh[0], fK[n][0], aK, 0, 0, 0);
            aK = __builtin_amdgcn_mfma_f32_16x16x32_bf16(Aoh[1], fK[n][1], aK, 0, 0, 0);
            f32x4 aV = (f32x4)(0.f);
            aV = __builtin_amdgcn_mfma_f32_16x16x32_bf16(Aoh[0], fV[n][0], aV, 0, 0, 0);
            aV = __builtin_amdgcn_mfma_f32_16x16x32_bf16(Aoh[1], fV[n][1], aV, 0, 0, 0);
            // epilogue: lane handles j = j0w + kg*4 + rr, d = dof
#pragma unroll
            for (int rr = 0; rr < 4; ++rr) {
                int j = j0w + kg * 4 + rr;
                unsigned ukv = kvp[j * DIM + dof];
                float kv = __uint_as_float(ukv & 0xffff0000u);
                float vv = __uint_as_float(ukv << 16);
                float rel2 = aW[rr] + aQ[rr] + kv * aK[rr];   // log2-domain
                float p = fexp2(rel2);
                stl[n] += p;
                sta[n] = fmaf(p, vv + aV[rr], sta[n]);
            }
        }
    }

    // merge kg subgroups within wave (plain sums), then across 8 waves
#pragma unroll
    for (int n = 0; n < 4; ++n) {
#pragma unroll
        for (int off = 16; off <= 32; off <<= 1) {
            stl[n] += __shfl_xor(stl[n], off);
            sta[n] += __shfl_xor(sta[n], off);
        }
        if (lane < 16) {
            smrg[w][n][l15][0] = stl[n];
            smrg[w][n][l15][1] = sta[n];
        }
    }
    __syncthreads();
    if (tid < DIM) {
        int n = tid >> 4, c = tid & 15;
        float l = 0.f, a = 0.f;
#pragma unroll
        for (int ww = 0; ww < 8; ++ww) {
            l += smrg[ww][n][c][0];
            a += smrg[ww][n][c][1];
        }
        float att = a / l;
        ws[WS_ATT + i * DIM + tid] = att;
        atomicAdd(ws + WS_MEAN + tid, att);
        unsigned u = __float_as_uint(att);
        unsigned key = (u & 0x80000000u) ? ~u : (u | 0x80000000u);
        atomicMax((unsigned*)ws + WS_MAXK + tid, key);
    }
}

// ------------------------------------------- final GEMM + LayerNorm + ReLU
__global__ void k_final(const float* __restrict__ ws, const float* __restrict__ Wd,
                        const float* __restrict__ bd, const float* __restrict__ lng,
                        const float* __restrict__ lnb, float* __restrict__ out) {
    __shared__ float xs[3 * DIM];
    __shared__ float hp[4][DIM];
    int i = blockIdx.x;
    int tid = threadIdx.x;            // 0..255
    int c = tid & 63, q = tid >> 6;
    if (tid < DIM) xs[tid] = ws[WS_ATT + i * DIM + tid];
    else if (tid < 2 * DIM) xs[tid] = ws[WS_MEAN + (tid - DIM)] * (1.0f / (float)N);
    else if (tid < 3 * DIM) {
        unsigned key = ((const unsigned*)ws)[WS_MAXK + (tid - 2 * DIM)];
        unsigned ub = (key & 0x80000000u) ? (key & 0x7fffffffu) : ~key;
        xs[tid] = __uint_as_float(ub);
    }
    __syncthreads();
    float p0 = (q == 0) ? bd[c] : 0.0f, p1 = 0.f;
#pragma unroll
    for (int kk = q * 48; kk < q * 48 + 48; kk += 2) {
        p0 += xs[kk] * Wd[kk * DIM + c];
        p1 += xs[kk + 1] * Wd[(kk + 1) * DIM + c];
    }
    hp[q][c] = p0 + p1;
    __syncthreads();
    if (tid < DIM) {
        float h = hp[0][tid] + hp[1][tid] + hp[2][tid] + hp[3][tid];
        float s = h;
#pragma unroll
        for (int off = 32; off >= 1; off >>= 1) s += __shfl_xor(s, off);
        float mu = s * (1.0f / DIM);
        float dif = h - mu;
        float s2 = dif * dif;
#pragma unroll
        for (int off = 32; off >= 1; off >>= 1) s2 += __shfl_xor(s2, off);
        float var = s2 * (1.0f / DIM);
        float rs = rsqrtf(var + 1e-5f);
        float o = dif * rs * lng[tid] + lnb[tid];
        out[i * DIM + tid] = fmaxf(o, 0.0f);
    }
}

// ---------------------------------------------------------------- launcher
extern "C" void kernel_launch(void* const* d_in, const int* in_sizes, int n_in,
                              void* d_out, int out_size, void* d_ws, size_t ws_size,
                              hipStream_t stream) {
    (void)in_sizes; (void)n_in; (void)out_size; (void)ws_size;
    const float* feat = (const float*)d_in[0];
    const float* dist = (const float*)d_in[1];
    const float* Wqkv = (const float*)d_in[2];
    const float* bqkv = (const float*)d_in[3];
    const float* Wg1  = (const float*)d_in[4];
    const float* bg1  = (const float*)d_in[5];
    const float* Wg2  = (const float*)d_in[6];
    const float* bg2  = (const float*)d_in[7];
    const float* tx   = (const float*)d_in[8];
    const float* ty   = (const float*)d_in[9];
    const float* tz   = (const float*)d_in[10];
    const float* Wd   = (const float*)d_in[11];
    const float* bd   = (const float*)d_in[12];
    const float* lng  = (const float*)d_in[13];
    const float* lnb  = (const float*)d_in[14];
    float* ws = (float*)d_ws;
    float* out = (float*)d_out;

    hipLaunchKernelGGL(k_qkv, dim3(N), dim3(192), 0, stream, feat, Wqkv, bqkv, Wg1, bg1, ws);
    hipLaunchKernelGGL(k_attn, dim3(N), dim3(512), 0, stream, dist, tx, ty, tz, Wg2, bg2, ws);
    hipLaunchKernelGGL(k_final, dim3(N), dim3(256), 0, stream, ws, Wd, bd, lng, lnb, out);
}